// Round 16
// baseline (180.230 us; speedup 1.0000x reference)
//
#include <hip/hip_runtime.h>
#include <stdint.h>

#define TT 16
#define BB 16
#define CC 256
#define HS 31
#define HT 15
#define OUTW 17
#define NCH 13                      // channels per block; 13*17 = 221/256 lanes in compute
#define NCHAN (BB*TT*CC)            // 65536
#define CORR_ELEMS ((size_t)NCHAN*OUTW*OUTW)
#define SROW 32                     // dwords per s row (f32, 128B, b128-aligned, XOR-swizzled)
#define SOFF 992                    // w block offset (31*32)
#define WROW 16                     // dwords per w row (15 data + 1 pad)
#define SCH  1236                   // dwords per channel (992 s + 240 w + 4 pad); 13*1236*4 = 64272 B

// logical channel ch = (b*T + t)*C + c  ->  s_f index (t*B + b)*C + c
__device__ __forceinline__ int s_index(int ch) {
    int bt = ch >> 8, c = ch & 255;
    int b = bt >> 4, t = bt & 15;
    return (t * BB + b) * CC + c;
}

__global__ __launch_bounds__(256, 2)
void corr_kernel(const float* __restrict__ s_f, const float* __restrict__ t_f,
                 const int* __restrict__ pos,
                 float* __restrict__ corr, float* __restrict__ masks)
{
    __shared__ float lds[NCH * SCH];   // 64272 B -> 2 blocks/CU

    const int tid = threadIdx.x;
    const int ch_base = blockIdx.x * NCH;

    // ---- stage s (f32, no packing): fire-and-forget loads, then swizzled writes ----
    // thread (r0 = tid>>4, jcol = tid&15) covers rows r0, r0+16, x = {2*jcol, 2*jcol+1}.
    // dst dword col for (y,x): (((x>>2) ^ (y&7)) << 2) | (x&3)  — pair stays in one 16B unit.
    {
        const int jcol = tid & 15;
        const int r0   = tid >> 4;          // 0..15
        const int x0   = 2 * jcol;
        const bool hasb  = (jcol < 15);     // jcol==15 -> only x=30 exists
        const int  r1    = r0 + 16;
        const bool hasr1 = (r1 <= 30);
        const int xa = hasb ? x0 : x0 - 1;  // shifted 8B load stays in-bounds at tail

        float2 La[NCH], Lb[NCH];
#pragma unroll
        for (int j = 0; j < NCH; ++j) {
            int ch = ch_base + j; if (ch >= NCHAN) ch = NCHAN - 1;
            const float* src = s_f + (size_t)s_index(ch) * (HS * HS);
            La[j] = *(const float2*)(src + r0 * HS + xa);
            Lb[j] = hasr1 ? *(const float2*)(src + r1 * HS + xa)
                          : make_float2(0.f, 0.f);
        }
        const int u0 = jcol >> 1;           // 16B unit of the pair
        const int lo = x0 & 3;              // 0 or 2 within unit
#pragma unroll
        for (int j = 0; j < NCH; ++j) {
            {
                int col = (((u0) ^ (r0 & 7)) << 2) | lo;
                if (hasb) {
                    *(float2*)&lds[j * SCH + r0 * SROW + col] = La[j];
                } else {
                    int c30 = ((7 ^ (r0 & 7)) << 2) | 2;
                    lds[j * SCH + r0 * SROW + c30] = La[j].y;   // x = 30
                }
            }
            if (hasr1) {
                if (hasb) {
                    int col = (((u0) ^ (r1 & 7)) << 2) | lo;
                    *(float2*)&lds[j * SCH + r1 * SROW + col] = Lb[j];
                } else {
                    int c30 = ((7 ^ (r1 & 7)) << 2) | 2;
                    lds[j * SCH + r1 * SROW + c30] = Lb[j].y;
                }
            }
        }
    }

    // ---- stage w (f32): w row ky = 16 dwords at SOFF + 16*ky (15 data + 0 pad) ----
    {
        float2 Lw[8];
        int    off[8];
#pragma unroll
        for (int it = 0; it < 8; ++it) {
            int idx = tid + 256 * it;               // < 1560 = NCH*HT*8 (tail masked)
            bool ok = idx < NCH * HT * 8;
            int i2  = ok ? idx : 0;
            int j   = i2 / (HT * 8);
            int e   = i2 - j * (HT * 8);
            int ky  = e >> 3, p = e & 7;
            int ch  = ch_base + j; if (ch >= NCHAN) ch = NCHAN - 1;
            int bt = ch >> 8, c = ch & 255, b = bt >> 4;
            const float* wsrc = t_f + (size_t)(b * CC + c) * (HT * HT) + ky * HT;
            int xw = (p < 7) ? 2 * p : 13;          // p==7: load (13,14), keep .y
            Lw[it] = *(const float2*)(wsrc + xw);
            if (p == 7) { Lw[it].x = Lw[it].y; Lw[it].y = 0.0f; }
            off[it] = ok ? (j * SCH + SOFF + ky * WROW + 2 * p) : -1;
        }
#pragma unroll
        for (int it = 0; it < 8; ++it)
            if (off[it] >= 0) *(float2*)&lds[off[it]] = Lw[it];
    }

    __syncthreads();

    // ---- compute: thread = (c_sub, oy) owns one 17-wide output row; pure v_fma_f32 ----
    const int c_sub = tid / OUTW;
    const int oy    = tid - c_sub * OUTW;
    if (c_sub >= NCH) return;
    const int ch = ch_base + c_sub;
    if (ch >= NCHAN) return;

    const float* chb = lds + c_sub * SCH;

    float acc[OUTW];
#pragma unroll
    for (int m = 0; m < OUTW; ++m) acc[m] = 0.0f;

#pragma unroll 1
    for (int ky = 0; ky < HT; ++ky) {
        const int y  = oy + ky;
        const int yb = y & 7;
        const float4* srow = (const float4*)(chb + y * SROW);

        float sv[32];
#pragma unroll
        for (int u = 0; u < 8; ++u) {
            float4 d = srow[u ^ yb];
            sv[4 * u + 0] = d.x; sv[4 * u + 1] = d.y;
            sv[4 * u + 2] = d.z; sv[4 * u + 3] = d.w;
        }

        const float4* wr = (const float4*)(chb + SOFF + ky * WROW);
        float wv[16];
#pragma unroll
        for (int u = 0; u < 4; ++u) {
            float4 d = wr[u];
            wv[4 * u + 0] = d.x; wv[4 * u + 1] = d.y;
            wv[4 * u + 2] = d.z; wv[4 * u + 3] = d.w;
        }

#pragma unroll
        for (int kx = 0; kx < HT; ++kx)
#pragma unroll
            for (int m = 0; m < OUTW; ++m)
                acc[m] = fmaf(sv[m + kx], wv[kx], acc[m]);
    }

    // ---- epilogue: corr row + fused masks gather ----
    float* outp = corr + (size_t)ch * (OUTW * OUTW) + (size_t)oy * OUTW;
#pragma unroll
    for (int m = 0; m < OUTW; ++m) outp[m] = acc[m];

    const int bt = ch >> 8;
    const int p0 = pos[2 * bt];
    const int p1 = pos[2 * bt + 1];
    if (oy == p0) {
        float v = acc[0];
#pragma unroll
        for (int m = 1; m < OUTW; ++m) v = (p1 == m) ? acc[m] : v;
        masks[ch] = v;
    }
}

extern "C" void kernel_launch(void* const* d_in, const int* in_sizes, int n_in,
                              void* d_out, int out_size, void* d_ws, size_t ws_size,
                              hipStream_t stream)
{
    const float* s_f = (const float*)d_in[0];
    const float* t_f = (const float*)d_in[1];
    const int*   pos = (const int*)d_in[2];
    float* corr  = (float*)d_out;
    float* masks = corr + CORR_ELEMS;

    int nblocks = (NCHAN + NCH - 1) / NCH;   // 5042
    corr_kernel<<<nblocks, 256, 0, stream>>>(s_f, t_f, pos, corr, masks);
}

// Round 17
// 178.407 us; speedup vs baseline: 1.0102x; 1.0102x over previous
//
#include <hip/hip_runtime.h>
#include <stdint.h>

#define TT 16
#define BB 16
#define CC 256
#define HS 31
#define HT 15
#define OUTW 17
#define NCH 13                      // channels per block; 13*17 = 221/256 lanes in compute
#define NCHAN (BB*TT*CC)            // 65536
#define CORR_ELEMS ((size_t)NCHAN*OUTW*OUTW)
#define SROW 32                     // dwords per s row (f32, 128B, b128-aligned, XOR-swizzled)
#define SOFF 992                    // w block offset (31*32)
#define WROW 16                     // dwords per w row (15 data + 1 pad)
#define SCH  1236                   // dwords per channel (992 s + 240 w + 4 pad); 13*1236*4 = 64272 B

// logical channel ch = (b*T + t)*C + c  ->  s_f index (t*B + b)*C + c
__device__ __forceinline__ int s_index(int ch) {
    int bt = ch >> 8, c = ch & 255;
    int b = bt >> 4, t = bt & 15;
    return (t * BB + b) * CC + c;
}

__global__ __launch_bounds__(256, 2)
void corr_kernel(const float* __restrict__ s_f, const float* __restrict__ t_f,
                 const int* __restrict__ pos,
                 float* __restrict__ corr, float* __restrict__ masks)
{
    __shared__ float lds[NCH * SCH];   // 64272 B -> 2 blocks/CU

    const int tid = threadIdx.x;
    const int ch_base = blockIdx.x * NCH;

    // ---- stage s (f32, no packing): fire-and-forget loads, then swizzled writes ----
    // thread (r0 = tid>>4, jcol = tid&15) covers rows r0, r0+16, x = {2*jcol, 2*jcol+1}.
    // dst dword col for (y,x): (((x>>2) ^ (y&7)) << 2) | (x&3)  — pair stays in one 16B unit.
    {
        const int jcol = tid & 15;
        const int r0   = tid >> 4;          // 0..15
        const int x0   = 2 * jcol;
        const bool hasb  = (jcol < 15);     // jcol==15 -> only x=30 exists
        const int  r1    = r0 + 16;
        const bool hasr1 = (r1 <= 30);
        const int xa = hasb ? x0 : x0 - 1;  // shifted 8B load stays in-bounds at tail

        float2 La[NCH], Lb[NCH];
#pragma unroll
        for (int j = 0; j < NCH; ++j) {
            int ch = ch_base + j; if (ch >= NCHAN) ch = NCHAN - 1;
            const float* src = s_f + (size_t)s_index(ch) * (HS * HS);
            La[j] = *(const float2*)(src + r0 * HS + xa);
            Lb[j] = hasr1 ? *(const float2*)(src + r1 * HS + xa)
                          : make_float2(0.f, 0.f);
        }
        const int u0 = jcol >> 1;           // 16B unit of the pair
        const int lo = x0 & 3;              // 0 or 2 within unit
#pragma unroll
        for (int j = 0; j < NCH; ++j) {
            {
                int col = (((u0) ^ (r0 & 7)) << 2) | lo;
                if (hasb) {
                    *(float2*)&lds[j * SCH + r0 * SROW + col] = La[j];
                } else {
                    int c30 = ((7 ^ (r0 & 7)) << 2) | 2;
                    lds[j * SCH + r0 * SROW + c30] = La[j].y;   // x = 30
                }
            }
            if (hasr1) {
                if (hasb) {
                    int col = (((u0) ^ (r1 & 7)) << 2) | lo;
                    *(float2*)&lds[j * SCH + r1 * SROW + col] = Lb[j];
                } else {
                    int c30 = ((7 ^ (r1 & 7)) << 2) | 2;
                    lds[j * SCH + r1 * SROW + c30] = Lb[j].y;
                }
            }
        }
    }

    // ---- stage w (f32): w row ky = 16 dwords at SOFF + 16*ky (15 data + 0 pad) ----
    {
        float2 Lw[8];
        int    off[8];
#pragma unroll
        for (int it = 0; it < 8; ++it) {
            int idx = tid + 256 * it;               // < 1560 = NCH*HT*8 (tail masked)
            bool ok = idx < NCH * HT * 8;
            int i2  = ok ? idx : 0;
            int j   = i2 / (HT * 8);
            int e   = i2 - j * (HT * 8);
            int ky  = e >> 3, p = e & 7;
            int ch  = ch_base + j; if (ch >= NCHAN) ch = NCHAN - 1;
            int bt = ch >> 8, c = ch & 255, b = bt >> 4;
            const float* wsrc = t_f + (size_t)(b * CC + c) * (HT * HT) + ky * HT;
            int xw = (p < 7) ? 2 * p : 13;          // p==7: load (13,14), keep .y
            Lw[it] = *(const float2*)(wsrc + xw);
            if (p == 7) { Lw[it].x = Lw[it].y; Lw[it].y = 0.0f; }
            off[it] = ok ? (j * SCH + SOFF + ky * WROW + 2 * p) : -1;
        }
#pragma unroll
        for (int it = 0; it < 8; ++it)
            if (off[it] >= 0) *(float2*)&lds[off[it]] = Lw[it];
    }

    __syncthreads();

    // ---- compute: thread = (c_sub, oy) owns one 17-wide output row; pure v_fma_f32 ----
    const int c_sub = tid / OUTW;
    const int oy    = tid - c_sub * OUTW;
    if (c_sub >= NCH) return;
    const int ch = ch_base + c_sub;
    if (ch >= NCHAN) return;

    const float* chb = lds + c_sub * SCH;

    float acc[OUTW];
#pragma unroll
    for (int m = 0; m < OUTW; ++m) acc[m] = 0.0f;

#pragma unroll 1
    for (int ky = 0; ky < HT; ++ky) {
        const int y  = oy + ky;
        const int yb = y & 7;
        const float4* srow = (const float4*)(chb + y * SROW);

        float sv[32];
#pragma unroll
        for (int u = 0; u < 8; ++u) {
            float4 d = srow[u ^ yb];
            sv[4 * u + 0] = d.x; sv[4 * u + 1] = d.y;
            sv[4 * u + 2] = d.z; sv[4 * u + 3] = d.w;
        }

        const float4* wr = (const float4*)(chb + SOFF + ky * WROW);
        float wv[16];
#pragma unroll
        for (int u = 0; u < 4; ++u) {
            float4 d = wr[u];
            wv[4 * u + 0] = d.x; wv[4 * u + 1] = d.y;
            wv[4 * u + 2] = d.z; wv[4 * u + 3] = d.w;
        }

#pragma unroll
        for (int kx = 0; kx < HT; ++kx)
#pragma unroll
            for (int m = 0; m < OUTW; ++m)
                acc[m] = fmaf(sv[m + kx], wv[kx], acc[m]);
    }

    // ---- epilogue: corr row + fused masks gather ----
    float* outp = corr + (size_t)ch * (OUTW * OUTW) + (size_t)oy * OUTW;
#pragma unroll
    for (int m = 0; m < OUTW; ++m) outp[m] = acc[m];

    const int bt = ch >> 8;
    const int p0 = pos[2 * bt];
    const int p1 = pos[2 * bt + 1];
    if (oy == p0) {
        float v = acc[0];
#pragma unroll
        for (int m = 1; m < OUTW; ++m) v = (p1 == m) ? acc[m] : v;
        masks[ch] = v;
    }
}

extern "C" void kernel_launch(void* const* d_in, const int* in_sizes, int n_in,
                              void* d_out, int out_size, void* d_ws, size_t ws_size,
                              hipStream_t stream)
{
    const float* s_f = (const float*)d_in[0];
    const float* t_f = (const float*)d_in[1];
    const int*   pos = (const int*)d_in[2];
    float* corr  = (float*)d_out;
    float* masks = corr + CORR_ELEMS;

    int nblocks = (NCHAN + NCH - 1) / NCH;   // 5042
    corr_kernel<<<nblocks, 256, 0, stream>>>(s_f, t_f, pos, corr, masks);
}